// Round 15
// baseline (615.704 us; speedup 1.0000x reference)
//
#include <hip/hip_runtime.h>

typedef __attribute__((ext_vector_type(4))) float f32x4;
typedef __attribute__((ext_vector_type(4))) int i32x4;
typedef __attribute__((ext_vector_type(8))) short short8;
typedef __attribute__((ext_vector_type(4))) short short4v;
typedef unsigned short u16;
typedef unsigned int u32;
typedef unsigned long long u64;

#define DEV static __device__ __forceinline__

DEV float bf2f(u16 u){ union { unsigned int i; float f; } v; v.i = ((unsigned int)u) << 16; return v.f; }
DEV u16 f2bf(float f){ union { float f; unsigned int i; } v; v.f = f; unsigned int r = v.i + 0x7fffu + ((v.i >> 16) & 1u); return (u16)(r >> 16); }
DEV float sigm(float x){ return 1.f / (1.f + expf(-x)); }

// write-through (agent-coherent) stores
DEV void stg_f32(float* p, float v){ __hip_atomic_store(p, v, __ATOMIC_RELAXED, __HIP_MEMORY_SCOPE_AGENT); }
DEV void stg_u16(u16* p, u16 v){ __hip_atomic_store(p, v, __ATOMIC_RELAXED, __HIP_MEMORY_SCOPE_AGENT); }
DEV void stg_u64(u64* p, u64 v){ __hip_atomic_store(p, v, __ATOMIC_RELAXED, __HIP_MEMORY_SCOPE_AGENT); }
// coherent reads (relaxed, agent scope)
DEV u64 ldg_u64(const u64* p){ return __hip_atomic_load(p, __ATOMIC_RELAXED, __HIP_MEMORY_SCOPE_AGENT); }
DEV float ldg_f32(const float* p){ return __hip_atomic_load(p, __ATOMIC_RELAXED, __HIP_MEMORY_SCOPE_AGENT); }

DEV short8 cvt8(const float* __restrict__ p){
    const f32x4* q = (const f32x4*)p;
    f32x4 lo = q[0], hi = q[1];
    short8 r;
    r[0]=(short)f2bf(lo[0]); r[1]=(short)f2bf(lo[1]); r[2]=(short)f2bf(lo[2]); r[3]=(short)f2bf(lo[3]);
    r[4]=(short)f2bf(hi[0]); r[5]=(short)f2bf(hi[1]); r[6]=(short)f2bf(hi[2]); r[7]=(short)f2bf(hi[3]);
    return r;
}

// LDS XOR swizzle (G4): spread 8-row stripes across 16B slots
DEV int swz2k(int row, int colb){ return (row * 2048 + colb) ^ ((row & 7) << 4); }
DEV int swz4k(int row, int colb){ return (row * 4096 + colb) ^ ((row & 7) << 4); }

// ---------------------------------------------------------------------------
// Distributed grid barrier (no L2 invalidation; rotated buffers make cached
// reads safe by construction — each address written once, read after barrier).
// ---------------------------------------------------------------------------
DEV void bar_arrive(u32* __restrict__ slots, u32 n, int bid, int tid)
{
    asm volatile("s_waitcnt vmcnt(0)" ::: "memory");
    __syncthreads();
    if (tid == 0)
        __hip_atomic_store(&slots[bid], n, __ATOMIC_RELAXED, __HIP_MEMORY_SCOPE_AGENT);
}

DEV void bar_wait(u32* __restrict__ slots, u32 n, int tid)
{
    if (tid < 64) {
        for (;;) {
            u32 v0 = __hip_atomic_load(&slots[tid*4+0], __ATOMIC_RELAXED, __HIP_MEMORY_SCOPE_AGENT);
            u32 v1 = __hip_atomic_load(&slots[tid*4+1], __ATOMIC_RELAXED, __HIP_MEMORY_SCOPE_AGENT);
            u32 v2 = __hip_atomic_load(&slots[tid*4+2], __ATOMIC_RELAXED, __HIP_MEMORY_SCOPE_AGENT);
            u32 v3 = __hip_atomic_load(&slots[tid*4+3], __ATOMIC_RELAXED, __HIP_MEMORY_SCOPE_AGENT);
            bool ok = (v0 >= n) && (v1 >= n) && (v2 >= n) && (v3 >= n);
            if (__all(ok)) break;
            __builtin_amdgcn_s_sleep(1);
        }
    }
    __syncthreads();
}

// ---------------------------------------------------------------------------
// k_prep: one-shot prep.
//   [0,2016)     gather emb rows -> xrow (bf16)
//   [2016,2272)  transpose W_attn_in -> WT (bf16)
//   [2272,2304)  init cF (fp32), hbR slot 0 (bf16)
//   [2304,6400)  cvt enc -> enc16
// ---------------------------------------------------------------------------
__global__ void __launch_bounds__(256)
k_prep(const float* __restrict__ enc, u16* __restrict__ enc16,
       const int* __restrict__ tgt, const float* __restrict__ emb, u16* __restrict__ xrow,
       const float* __restrict__ Wai, u16* __restrict__ WT,
       const float* __restrict__ h0, const float* __restrict__ c0,
       float* __restrict__ cF, u16* __restrict__ hbR)
{
    const int bid = blockIdx.x, tid = threadIdx.x;
    __shared__ u16 tl[64][65];
    if (bid < 2016) {
        int r = bid;
        int t = r >> 5, b = r & 31;
        const float* src = emb + (size_t)tgt[b * 64 + t] * 1024;
        int j = tid * 4;
        f32x4 v = *(const f32x4*)(src + j);
        short4v o;
        o[0]=(short)f2bf(v[0]); o[1]=(short)f2bf(v[1]);
        o[2]=(short)f2bf(v[2]); o[3]=(short)f2bf(v[3]);
        *(short4v*)(xrow + (size_t)r * 1024 + j) = o;
    } else if (bid < 2272) {
        int tb = bid - 2016;
        int ti = tb >> 4, tj = tb & 15;
        int rr = tid >> 2, cc = (tid & 3) * 16;
        for (int i = 0; i < 16; ++i)
            tl[rr][cc + i] = f2bf(Wai[(size_t)(ti * 64 + rr) * 1024 + tj * 64 + cc + i]);
        __syncthreads();
        for (int i = 0; i < 16; ++i)
            WT[(size_t)(tj * 64 + rr) * 1024 + ti * 64 + cc + i] = tl[cc + i][rr];
    } else if (bid < 2304) {
        int b = bid - 2272;
        int j = tid * 4;
        for (int i = 0; i < 4; ++i) {
            int k = j + i;
            float hv = (k < 512) ? h0[(size_t)b * 512 + k] : h0[(size_t)(32 + b) * 512 + (k - 512)];
            float cv = (k < 512) ? c0[(size_t)b * 512 + k] : c0[(size_t)(32 + b) * 512 + (k - 512)];
            cF[b * 1024 + k] = cv;
            hbR[b * 1024 + k] = f2bf(hv);   // slot 0 = h_0
        }
    } else {
        size_t i = (size_t)(bid - 2304) * 1024 + tid * 4;
        f32x4 v = *(const f32x4*)(enc + i);
        short4v o;
        o[0]=(short)f2bf(v[0]); o[1]=(short)f2bf(v[1]);
        o[2]=(short)f2bf(v[2]); o[3]=(short)f2bf(v[3]);
        *(short4v*)(enc16 + i) = o;
    }
}

// ---------------------------------------------------------------------------
// k_mm: xg-GEMM [0,512) and M-GEMM [512,768), LDS B-panels (round-14 proven).
// ---------------------------------------------------------------------------
__global__ void __launch_bounds__(512, 1)
k_mm(const u16* __restrict__ xrow, const float* __restrict__ Wih,
     const float* __restrict__ bih, const float* __restrict__ bhh, u16* __restrict__ xg,
     const u16* __restrict__ enc16, const u16* __restrict__ WT, float* __restrict__ Mf)
{
    extern __shared__ char Bl[];
    const int tid = threadIdx.x;
    const int wv = tid >> 6, l = tid & 63, lr = l & 15, lq = l >> 4;
    const int bx = blockIdx.x;
    const bool isXG = bx < 512;
    int mt, nt;
    const u16* Asrc;
    if (isXG) { mt = bx & 7;          nt = bx >> 3; Asrc = xrow;  }
    else      { int mb = bx - 512; mt = mb & 15; nt = mb >> 4; Asrc = enc16; }

    if (isXG) {
        for (int u = tid; u < 8192; u += 512) {
            int row = u >> 7, c8 = (u & 127) * 8;
            *(short8*)(Bl + swz2k(row, c8 * 2)) = cvt8(Wih + (size_t)(nt * 64 + row) * 1024 + c8);
        }
    } else {
        for (int u = tid; u < 8192; u += 512) {
            int row = u >> 7, c8 = (u & 127) * 8;
            *(short8*)(Bl + swz2k(row, c8 * 2)) = *(const short8*)(WT + (size_t)(nt * 64 + row) * 1024 + c8);
        }
    }
    __syncthreads();

    const int r0 = mt * 256 + wv * 32;
    int rA0 = r0 + lr, rA1 = r0 + 16 + lr;
    if (isXG) { if (rA0 > 2015) rA0 = 2015; if (rA1 > 2015) rA1 = 2015; }
    const u16* a0 = Asrc + (size_t)rA0 * 1024 + lq * 8;
    const u16* a1 = Asrc + (size_t)rA1 * 1024 + lq * 8;
    short8 aq0[4], aq1[4];
#pragma unroll
    for (int d = 0; d < 4; ++d) {
        aq0[d] = *(const short8*)(a0 + d * 32);
        aq1[d] = *(const short8*)(a1 + d * 32);
    }
    f32x4 acc[2][4];
#pragma unroll
    for (int rg = 0; rg < 2; ++rg)
#pragma unroll
        for (int nf = 0; nf < 4; ++nf) acc[rg][nf] = (f32x4){0.f, 0.f, 0.f, 0.f};

#pragma unroll
    for (int k = 0; k < 32; ++k) {
        short8 av0 = aq0[k & 3], av1 = aq1[k & 3];
        if (k + 4 < 32) {
            aq0[k & 3] = *(const short8*)(a0 + (k + 4) * 32);
            aq1[k & 3] = *(const short8*)(a1 + (k + 4) * 32);
        }
#pragma unroll
        for (int nf = 0; nf < 4; ++nf) {
            short8 bv = *(const short8*)(Bl + swz2k(nf * 16 + lr, (lq * 8 + k * 32) * 2));
            acc[0][nf] = __builtin_amdgcn_mfma_f32_16x16x32_bf16(av0, bv, acc[0][nf], 0, 0, 0);
            acc[1][nf] = __builtin_amdgcn_mfma_f32_16x16x32_bf16(av1, bv, acc[1][nf], 0, 0, 0);
        }
    }

    if (isXG) {
#pragma unroll
        for (int rg = 0; rg < 2; ++rg)
#pragma unroll
        for (int nf = 0; nf < 4; ++nf) {
            int n = nt * 64 + nf * 16 + lr;
            float bias = bih[n] + bhh[n];
#pragma unroll
            for (int q = 0; q < 4; ++q) {
                int rr = r0 + rg * 16 + lq * 4 + q;
                if (rr < 2016) xg[(size_t)rr * 4096 + n] = f2bf(acc[rg][nf][q] + bias);
            }
        }
    } else {
#pragma unroll
        for (int rg = 0; rg < 2; ++rg)
#pragma unroll
        for (int nf = 0; nf < 4; ++nf) {
            int n = nt * 64 + nf * 16 + lr;
#pragma unroll
            for (int q = 0; q < 4; ++q)
                Mf[(size_t)(r0 + rg * 16 + lq * 4 + q) * 1024 + n] = acc[rg][nf][q];
        }
    }
}

// ---------------------------------------------------------------------------
// combine 16 half-chunk partials -> ctxA[tstore] (tid<32)
// ---------------------------------------------------------------------------
DEV void combine16(int b, int ch, int tstore, int tid, int slot,
                   const float* __restrict__ pCtx, const float* __restrict__ pMx,
                   const float* __restrict__ pSm, u16* __restrict__ ctxA)
{
    if (tid >= 32) return;
    const float* mx = pMx + (size_t)slot * 512 + b * 16;
    const float* sm = pSm + (size_t)slot * 512 + b * 16;
    const float* pc = pCtx + (size_t)slot * (32 * 16 * 1024) + (size_t)b * 16 * 1024;
    float m16[16], s16[16];
#pragma unroll
    for (int c = 0; c < 16; ++c) { m16[c] = ldg_f32(mx + c); s16[c] = ldg_f32(sm + c); }
    float gm = -1e30f;
#pragma unroll
    for (int c = 0; c < 16; ++c) gm = fmaxf(gm, m16[c]);
    float wsum = 0.f, e[16];
#pragma unroll
    for (int c = 0; c < 16; ++c) { e[c] = expf(m16[c] - gm); wsum += s16[c] * e[c]; }
    float inv = 1.f / wsum;
    int j = ch * 128 + tid * 4;
    f32x4 a = {0.f, 0.f, 0.f, 0.f};
#pragma unroll
    for (int c = 0; c < 16; ++c) {
        union { u64 q[2]; f32x4 v; } u;
        const u64* p = (const u64*)(pc + (size_t)c * 1024 + j);
        u.q[0] = ldg_u64(p); u.q[1] = ldg_u64(p + 1);
        float s = e[c] * inv;
        a[0] += u.v[0] * s; a[1] += u.v[1] * s; a[2] += u.v[2] * s; a[3] += u.v[3] * s;
    }
    short4v o4;
    o4[0] = (short)f2bf(a[0]); o4[1] = (short)f2bf(a[1]);
    o4[2] = (short)f2bf(a[2]); o4[3] = (short)f2bf(a[3]);
    *(short4v*)(ctxA + ((size_t)tstore * 32 + b) * 1024 + j) = o4;
}

// ---------------------------------------------------------------------------
// k_loop: wave-specialized persistent kernel. NEW: step-rotated h buffers
// (hbR[64], hFh[64]) -> consumers use plain CACHED loads (L2-shared per XCD).
// ---------------------------------------------------------------------------
#define ML_PITCH 1028
#define EL_PITCH 1032
#define ML_BYTES (16 * ML_PITCH * 4)
#define EL_BYTES (16 * EL_PITCH * 2)
#define DYN_BYTES (ML_BYTES + EL_BYTES)

__global__ void __launch_bounds__(256, 1)
k_loop(const u16* __restrict__ xg, const float* __restrict__ Mf,
       u16* __restrict__ ctxA, u16* __restrict__ hAll,
       u16* __restrict__ hbR, float* __restrict__ hFh, float* __restrict__ cF,
       float* __restrict__ pCtx, float* __restrict__ pMx, float* __restrict__ pSm,
       const float* __restrict__ enc, const float* __restrict__ Whh,
       const int* __restrict__ slen, float* __restrict__ out, u32* __restrict__ bar)
{
    const int bid = blockIdx.x, tid = threadIdx.x;
    const int wv = tid >> 6, l = tid & 63, lr = l & 15, lq = l >> 4;
    u32* slots = bar;

    extern __shared__ char smem[];
    float* Ml = (float*)smem;                 // [16][ML_PITCH]
    u16*   El = (u16*)(smem + ML_BYTES);      // [16][EL_PITCH]

    __shared__ float red[2][32][16];

    const int b_at = bid >> 3, ch = bid & 7, s0 = ch * 16;

    // ---- prologue ----
    short8 breg[16];
    if (wv < 2) {
        const float* wsrc = Whh + ((size_t)((lr >> 2) * 1024 + bid * 4 + (lr & 3))) * 1024
                                + wv * 512 + lq * 8;
#pragma unroll
        for (int ks = 0; ks < 16; ++ks)
            breg[ks] = cvt8(wsrc + ks * 32);
    }
    {   // M slice (fp32)
        int row = tid >> 4;
        const float* src = Mf + (size_t)(b_at * 128 + s0 + row) * 1024;
        float* dst = &Ml[row * ML_PITCH];
#pragma unroll
        for (int i = 0; i < 16; ++i) {
            int c = (tid & 15) * 4 + i * 64;
            *(f32x4*)(dst + c) = *(const f32x4*)(src + c);
        }
    }
    {   // enc slice (bf16)
        int row = tid >> 4;
        const float* src = enc + (size_t)(b_at * 128 + s0 + row) * 1024;
        u16* dst = &El[row * EL_PITCH];
#pragma unroll
        for (int i = 0; i < 16; ++i) {
            int c = (tid & 15) * 4 + i * 64;
            f32x4 v = *(const f32x4*)(src + c);
            short4v o;
            o[0]=(short)f2bf(v[0]); o[1]=(short)f2bf(v[1]);
            o[2]=(short)f2bf(v[2]); o[3]=(short)f2bf(v[3]);
            *(short4v*)(dst + c) = o;
        }
    }

    const int lb = tid & 31, lkk = (tid >> 5) - 4;
    const int lkidx = bid * 4 + lkk;
    float creg = 0.f;
    float xgv[4] = {0,0,0,0};
    if (tid >= 128) {
        creg = cF[lb * 1024 + lkidx];
#pragma unroll
        for (int g = 0; g < 4; ++g)
            xgv[g] = bf2f(xg[((size_t)lb) * 4096 + g * 1024 + lkidx]);   // t=0
    }
    int vlen = slen[b_at]; if (vlen < 1) vlen = 1;
    __syncthreads();

    for (int t = 0; t < 64; ++t) {
        if (t >= 1) bar_wait(slots, (u32)t, tid);

        if (t < 63 && wv < 2) {
            // ---- gates GEMM (waves 0-1, K split 2-way) — CACHED A-loads ----
            const u16* hrd = hbR + (size_t)t * 32768;
            const u16* p0 = hrd + lr * 1024 + wv * 512 + lq * 8;
            const u16* p1 = p0 + 16 * 1024;
            short8 a0b[16], a1b[16];
#pragma unroll
            for (int ks = 0; ks < 16; ++ks) {
                a0b[ks] = *(const short8*)(p0 + ks * 32);
                a1b[ks] = *(const short8*)(p1 + ks * 32);
            }
            f32x4 acc0 = {0,0,0,0}, acc1 = {0,0,0,0};
#pragma unroll
            for (int ks = 0; ks < 16; ++ks) {
                acc0 = __builtin_amdgcn_mfma_f32_16x16x32_bf16(a0b[ks], breg[ks], acc0, 0, 0, 0);
                acc1 = __builtin_amdgcn_mfma_f32_16x16x32_bf16(a1b[ks], breg[ks], acc1, 0, 0, 0);
            }
#pragma unroll
            for (int q = 0; q < 4; ++q) {
                red[wv][lq * 4 + q][lr] = acc0[q];
                red[wv][16 + lq * 4 + q][lr] = acc1[q];
            }
        }

        if (t >= 1 && wv >= 2) {
            // ---- attention for h_t (waves 2-3) — CACHED h loads ----
            const int w = wv - 2;
            const int lane = l;
            const float* hrow = hFh + (size_t)t * 32768 + b_at * 1024;
            f32x4 hreg[4];
            hreg[0] = *(const f32x4*)(hrow + 0 * 256 + lane * 4);
            hreg[1] = *(const f32x4*)(hrow + 1 * 256 + lane * 4);
            hreg[2] = *(const f32x4*)(hrow + 2 * 256 + lane * 4);
            hreg[3] = *(const f32x4*)(hrow + 3 * 256 + lane * 4);
            float part[8];
#pragma unroll
            for (int r = 0; r < 8; ++r) {
                const float* mrow = &Ml[(w * 8 + r) * ML_PITCH];
                float s = 0.f;
#pragma unroll
                for (int c = 0; c < 4; ++c) {
                    f32x4 m4 = *(const f32x4*)(mrow + c * 256 + lane * 4);
                    s += m4[0]*hreg[c][0] + m4[1]*hreg[c][1] + m4[2]*hreg[c][2] + m4[3]*hreg[c][3];
                }
                part[r] = s;
            }
#pragma unroll
            for (int d = 1; d < 64; d <<= 1) {
#pragma unroll
                for (int r = 0; r < 8; ++r) part[r] += __shfl_xor(part[r], d);
            }
            int sgb = s0 + w * 8;
            float mc = -1e30f;
#pragma unroll
            for (int r = 0; r < 8; ++r) {
                part[r] = (sgb + r < vlen) ? part[r] : -1e30f;
                mc = fmaxf(mc, part[r]);
            }
            float e8[8]; float psum = 0.f;
#pragma unroll
            for (int r = 0; r < 8; ++r) {
                e8[r] = (part[r] > -1e29f) ? expf(part[r] - mc) : 0.f;
                psum += e8[r];
            }
            f32x4 ca[4] = {{0,0,0,0},{0,0,0,0},{0,0,0,0},{0,0,0,0}};
#pragma unroll
            for (int r = 0; r < 8; ++r) {
                float p = e8[r];
                const u16* erow = &El[(w * 8 + r) * EL_PITCH];
#pragma unroll
                for (int c = 0; c < 4; ++c) {
                    short4v e4 = *(const short4v*)(erow + c * 256 + lane * 4);
                    ca[c][0] += p * bf2f((u16)e4[0]);
                    ca[c][1] += p * bf2f((u16)e4[1]);
                    ca[c][2] += p * bf2f((u16)e4[2]);
                    ca[c][3] += p * bf2f((u16)e4[3]);
                }
            }
            float* pd = pCtx + (size_t)(t & 3) * (32 * 16 * 1024)
                             + (size_t)(b_at * 16 + ch * 2 + w) * 1024;
#pragma unroll
            for (int c = 0; c < 4; ++c) {
                union { f32x4 v; u64 q[2]; } cu; cu.v = ca[c];
                u64* p = (u64*)(pd + c * 256 + lane * 4);
                stg_u64(p, cu.q[0]);
                stg_u64(p + 1, cu.q[1]);
            }
            if (lane == 0) {
                stg_f32(&pMx[(size_t)(t & 3) * 512 + b_at * 16 + ch * 2 + w], mc);
                stg_f32(&pSm[(size_t)(t & 3) * 512 + b_at * 16 + ch * 2 + w], psum);
            }
        }
        __syncthreads();

        if (t < 63 && tid >= 128) {
            // ---- LSTM elementwise ----
            float G[4];
#pragma unroll
            for (int g = 0; g < 4; ++g) {
                int n = g * 4 + lkk;
                G[g] = red[0][lb][n] + red[1][lb][n] + xgv[g];
            }
            float iS = sigm(G[0]), fS = sigm(G[1]), gT = tanhf(G[2]), oS = sigm(G[3]);
            float cn = fS * creg + iS * gT;
            float hn = oS * tanhf(cn);
            creg = cn;
            u16 h16 = f2bf(hn);
            stg_f32(&hFh[(size_t)(t + 1) * 32768 + lb * 1024 + lkidx], hn);
            stg_u16(&hbR[(size_t)(t + 1) * 32768 + lb * 1024 + lkidx], h16);
            hAll[((size_t)t * 32 + lb) * 1024 + lkidx] = h16;
        }

        bar_arrive(slots, (u32)(t + 1), bid, tid);

        // ---- shadow: combine + xg prefetch overlap barrier propagation ----
        if (t >= 2)
            combine16(b_at, ch, t - 2, tid, (t - 1) & 3, pCtx, pMx, pSm, ctxA);
        if (t < 62 && tid >= 128) {
#pragma unroll
            for (int g = 0; g < 4; ++g)
                xgv[g] = bf2f(xg[((size_t)(t + 1) * 32 + lb) * 4096 + g * 1024 + lkidx]);
        }
    }

    bar_wait(slots, 64u, tid);
    combine16(b_at, ch, 62, tid, 3, pCtx, pMx, pSm, ctxA);
    if (bid >= 32 && bid < 64) {
        int b = bid - 32, j = tid * 4;
#pragma unroll
        for (int i = 0; i < 4; ++i)
            out[2064384 + b * 1024 + j + i] = ldg_f32(&hFh[(size_t)63 * 32768 + b * 1024 + j + i]);
    }
    if (tid >= 128)
        out[2064384 + 32768 + lb * 1024 + lkidx] = creg;
}

// ---------------------------------------------------------------------------
// k_out: output GEMM, tile 256x32, LDS B-panel (round-14 proven).
// ---------------------------------------------------------------------------
__global__ void __launch_bounds__(512, 1)
k_out(const u16* __restrict__ ctxA, const u16* __restrict__ hAll,
      const float* __restrict__ Wao, float* __restrict__ out)
{
    extern __shared__ char Bl[];
    const int tid = threadIdx.x;
    const int wv = tid >> 6, l = tid & 63, lr = l & 15, lq = l >> 4;
    const int bx = blockIdx.x;
    const int mt = bx & 7, nt = bx >> 3;   // 8 m-tiles x 32 n-tiles

    for (int u = tid; u < 8192; u += 512) {
        int row = u >> 8, c8 = (u & 255) * 8;
        *(short8*)(Bl + swz4k(row, c8 * 2)) = cvt8(Wao + (size_t)(nt * 32 + row) * 2048 + c8);
    }
    __syncthreads();

    const int r0 = mt * 256 + wv * 32;
    int rA0 = r0 + lr;       if (rA0 > 2015) rA0 = 2015;
    int rA1 = r0 + 16 + lr;  if (rA1 > 2015) rA1 = 2015;
    const u16* ac0 = ctxA + (size_t)rA0 * 1024 + lq * 8;
    const u16* ah0 = hAll + (size_t)rA0 * 1024 + lq * 8;
    const u16* ac1 = ctxA + (size_t)rA1 * 1024 + lq * 8;
    const u16* ah1 = hAll + (size_t)rA1 * 1024 + lq * 8;

    short8 aq0[4], aq1[4];
#pragma unroll
    for (int d = 0; d < 4; ++d) {
        aq0[d] = *(const short8*)(ac0 + d * 32);
        aq1[d] = *(const short8*)(ac1 + d * 32);
    }
    f32x4 acc[2][2];
#pragma unroll
    for (int rg = 0; rg < 2; ++rg)
#pragma unroll
        for (int nf = 0; nf < 2; ++nf) acc[rg][nf] = (f32x4){0.f, 0.f, 0.f, 0.f};

#pragma unroll
    for (int k = 0; k < 64; ++k) {
        short8 av0 = aq0[k & 3], av1 = aq1[k & 3];
        if (k + 4 < 64) {
            int kn = k + 4;
            if (kn < 32) {
                aq0[k & 3] = *(const short8*)(ac0 + kn * 32);
                aq1[k & 3] = *(const short8*)(ac1 + kn * 32);
            } else {
                aq0[k & 3] = *(const short8*)(ah0 + (kn - 32) * 32);
                aq1[k & 3] = *(const short8*)(ah1 + (kn - 32) * 32);
            }
        }
#pragma unroll
        for (int nf = 0; nf < 2; ++nf) {
            short8 bv = *(const short8*)(Bl + swz4k(nf * 16 + lr, (lq * 8 + k * 32) * 2));
            acc[0][nf] = __builtin_amdgcn_mfma_f32_16x16x32_bf16(av0, bv, acc[0][nf], 0, 0, 0);
            acc[1][nf] = __builtin_amdgcn_mfma_f32_16x16x32_bf16(av1, bv, acc[1][nf], 0, 0, 0);
        }
    }
#pragma unroll
    for (int rg = 0; rg < 2; ++rg)
#pragma unroll
    for (int nf = 0; nf < 2; ++nf) {
        int n = nt * 32 + nf * 16 + lr;
#pragma unroll
        for (int q = 0; q < 4; ++q) {
            int rr = r0 + rg * 16 + lq * 4 + q;
            if (rr < 2016) {
                int t = rr >> 5, b = rr & 31;
                out[(size_t)b * 64512 + t * 1024 + n] = tanhf(acc[rg][nf][q]);
            }
        }
    }
}

// ---------------------------------------------------------------------------
extern "C" void kernel_launch(void* const* d_in, const int* in_sizes, int n_in,
                              void* d_out, int out_size, void* d_ws, size_t ws_size,
                              hipStream_t stream)
{
    (void)in_sizes; (void)n_in; (void)out_size; (void)ws_size;
    const int*   tgt  = (const int*)d_in[0];
    const float* h0   = (const float*)d_in[1];
    const float* c0   = (const float*)d_in[2];
    const float* enc  = (const float*)d_in[3];
    const int*   slen = (const int*)d_in[4];
    const float* emb  = (const float*)d_in[5];
    const float* Wih  = (const float*)d_in[6];
    const float* Whh  = (const float*)d_in[7];
    const float* bih  = (const float*)d_in[8];
    const float* bhh  = (const float*)d_in[9];
    const float* Wai  = (const float*)d_in[10];
    const float* Wao  = (const float*)d_in[11];
    float* out = (float*)d_out;

    char* ws = (char*)d_ws;
    size_t off = 0;
    auto alloc = [&](size_t bytes) -> char* {
        char* p = ws + off; off += (bytes + 255) & ~(size_t)255; return p;
    };
    u16*   enc16 = (u16*)  alloc(4096UL * 1024 * 2);
    u16*   xrow  = (u16*)  alloc(2016UL * 1024 * 2);
    u16*   WT    = (u16*)  alloc(1024UL * 1024 * 2);
    u16*   xg    = (u16*)  alloc(2016UL * 4096 * 2);
    float* Mf    = (float*)alloc(4096UL * 1024 * 4);
    u16*   hbR   = (u16*)  alloc(64UL * 32 * 1024 * 2);
    float* hFh   = (float*)alloc(64UL * 32 * 1024 * 4);
    float* cF    = (float*)alloc(32UL * 1024 * 4);
    u16*   hAll  = (u16*)  alloc(2016UL * 1024 * 2);
    u16*   ctxA  = (u16*)  alloc(2016UL * 1024 * 2);
    float* pCtx  = (float*)alloc(4UL * 32 * 16 * 1024 * 4);
    float* pMx   = (float*)alloc(4UL * 512 * 4);
    float* pSm   = (float*)alloc(4UL * 512 * 4);
    u32*   bar   = (u32*)  alloc(2048);

    static int lds_set = 0;
    if (!lds_set) {
        (void)hipFuncSetAttribute((const void*)k_loop,
                                  hipFuncAttributeMaxDynamicSharedMemorySize, DYN_BYTES);
        (void)hipFuncSetAttribute((const void*)k_mm,
                                  hipFuncAttributeMaxDynamicSharedMemorySize, 131072);
        (void)hipFuncSetAttribute((const void*)k_out,
                                  hipFuncAttributeMaxDynamicSharedMemorySize, 131072);
        lds_set = 1;
    }

    hipMemsetAsync(bar, 0, 2048, stream);
    hipLaunchKernelGGL(k_prep, dim3(6400), dim3(256), 0, stream,
                       enc, enc16, tgt, emb, xrow, Wai, WT, h0, c0, cF, hbR);
    hipLaunchKernelGGL(k_mm, dim3(768), dim3(512), 131072, stream,
                       xrow, Wih, bih, bhh, xg, enc16, WT, Mf);

    void* kargs[] = { (void*)&xg, (void*)&Mf, (void*)&ctxA, (void*)&hAll, (void*)&hbR,
                      (void*)&hFh, (void*)&cF, (void*)&pCtx, (void*)&pMx, (void*)&pSm,
                      (void*)&enc, (void*)&Whh, (void*)&slen, (void*)&out, (void*)&bar };
    hipLaunchCooperativeKernel((const void*)k_loop, dim3(256), dim3(256), kargs, DYN_BYTES, stream);

    hipLaunchKernelGGL(k_out, dim3(256), dim3(512), 131072, stream, ctxA, hAll, Wao, out);
}

// Round 16
// 550.834 us; speedup vs baseline: 1.1178x; 1.1178x over previous
//
#include <hip/hip_runtime.h>

typedef __attribute__((ext_vector_type(4))) float f32x4;
typedef __attribute__((ext_vector_type(4))) int i32x4;
typedef __attribute__((ext_vector_type(8))) short short8;
typedef __attribute__((ext_vector_type(4))) short short4v;
typedef unsigned short u16;
typedef unsigned int u32;
typedef unsigned long long u64;

#define DEV static __device__ __forceinline__

DEV float bf2f(u16 u){ union { unsigned int i; float f; } v; v.i = ((unsigned int)u) << 16; return v.f; }
DEV u16 f2bf(float f){ union { float f; unsigned int i; } v; v.f = f; unsigned int r = v.i + 0x7fffu + ((v.i >> 16) & 1u); return (u16)(r >> 16); }
DEV float sigm(float x){ return 1.f / (1.f + expf(-x)); }

// write-through (agent-coherent) stores
DEV void stg_f32(float* p, float v){ __hip_atomic_store(p, v, __ATOMIC_RELAXED, __HIP_MEMORY_SCOPE_AGENT); }
DEV void stg_u16(u16* p, u16 v){ __hip_atomic_store(p, v, __ATOMIC_RELAXED, __HIP_MEMORY_SCOPE_AGENT); }
DEV void stg_u64(u64* p, u64 v){ __hip_atomic_store(p, v, __ATOMIC_RELAXED, __HIP_MEMORY_SCOPE_AGENT); }
// coherent reads (relaxed, agent scope)
DEV u64 ldg_u64(const u64* p){ return __hip_atomic_load(p, __ATOMIC_RELAXED, __HIP_MEMORY_SCOPE_AGENT); }
DEV float ldg_f32(const float* p){ return __hip_atomic_load(p, __ATOMIC_RELAXED, __HIP_MEMORY_SCOPE_AGENT); }
// cache-bypassing 16B load (issue only; caller does s_waitcnt + sched_barrier)
DEV void ldcc4i(i32x4* d, const void* p){
    asm volatile("global_load_dwordx4 %0, %1, off sc0 sc1" : "=v"(*d) : "v"(p) : "memory");
}
DEV void ldcc4f(f32x4* d, const void* p){
    asm volatile("global_load_dwordx4 %0, %1, off sc0 sc1" : "=v"(*d) : "v"(p) : "memory");
}
DEV short8 as_s8(i32x4 v){ union{ i32x4 i; short8 s; } u; u.i = v; return u.s; }

DEV short8 cvt8(const float* __restrict__ p){
    const f32x4* q = (const f32x4*)p;
    f32x4 lo = q[0], hi = q[1];
    short8 r;
    r[0]=(short)f2bf(lo[0]); r[1]=(short)f2bf(lo[1]); r[2]=(short)f2bf(lo[2]); r[3]=(short)f2bf(lo[3]);
    r[4]=(short)f2bf(hi[0]); r[5]=(short)f2bf(hi[1]); r[6]=(short)f2bf(hi[2]); r[7]=(short)f2bf(hi[3]);
    return r;
}

// LDS XOR swizzle (G4): spread 8-row stripes across 16B slots
DEV int swz2k(int row, int colb){ return (row * 2048 + colb) ^ ((row & 7) << 4); }
DEV int swz4k(int row, int colb){ return (row * 4096 + colb) ^ ((row & 7) << 4); }

// ---------------------------------------------------------------------------
// Distributed grid barrier (no L2 invalidation; shared data read sc0/sc1).
// bar_wait: ONE volatile dwordx4 poll per lane (4x less poll traffic than
// 4 separate atomic dword loads).
// ---------------------------------------------------------------------------
DEV void bar_arrive(u32* __restrict__ slots, u32 n, int bid, int tid)
{
    asm volatile("s_waitcnt vmcnt(0)" ::: "memory");
    __syncthreads();
    if (tid == 0)
        __hip_atomic_store(&slots[bid], n, __ATOMIC_RELAXED, __HIP_MEMORY_SCOPE_AGENT);
}

DEV void bar_wait(u32* __restrict__ slots, u32 n, int tid)
{
    if (tid < 64) {
        const void* p = slots + tid * 4;
        for (;;) {
            i32x4 v;
            ldcc4i(&v, p);
            asm volatile("s_waitcnt vmcnt(0)" ::: "memory");
            bool ok = ((u32)v[0] >= n) && ((u32)v[1] >= n) &&
                      ((u32)v[2] >= n) && ((u32)v[3] >= n);
            if (__all(ok)) break;
            __builtin_amdgcn_s_sleep(1);
        }
    }
    __syncthreads();
}

// ---------------------------------------------------------------------------
// k_prep: one-shot prep.
//   [0,2016)     gather emb rows -> xrow (bf16)
//   [2016,2272)  transpose W_attn_in -> WT (bf16)
//   [2272,2304)  init cF (fp32), hb buf0 (bf16)
//   [2304,6400)  cvt enc -> enc16
// ---------------------------------------------------------------------------
__global__ void __launch_bounds__(256)
k_prep(const float* __restrict__ enc, u16* __restrict__ enc16,
       const int* __restrict__ tgt, const float* __restrict__ emb, u16* __restrict__ xrow,
       const float* __restrict__ Wai, u16* __restrict__ WT,
       const float* __restrict__ h0, const float* __restrict__ c0,
       float* __restrict__ cF, u16* __restrict__ hb)
{
    const int bid = blockIdx.x, tid = threadIdx.x;
    __shared__ u16 tl[64][65];
    if (bid < 2016) {
        int r = bid;
        int t = r >> 5, b = r & 31;
        const float* src = emb + (size_t)tgt[b * 64 + t] * 1024;
        int j = tid * 4;
        f32x4 v = *(const f32x4*)(src + j);
        short4v o;
        o[0]=(short)f2bf(v[0]); o[1]=(short)f2bf(v[1]);
        o[2]=(short)f2bf(v[2]); o[3]=(short)f2bf(v[3]);
        *(short4v*)(xrow + (size_t)r * 1024 + j) = o;
    } else if (bid < 2272) {
        int tb = bid - 2016;
        int ti = tb >> 4, tj = tb & 15;
        int rr = tid >> 2, cc = (tid & 3) * 16;
        for (int i = 0; i < 16; ++i)
            tl[rr][cc + i] = f2bf(Wai[(size_t)(ti * 64 + rr) * 1024 + tj * 64 + cc + i]);
        __syncthreads();
        for (int i = 0; i < 16; ++i)
            WT[(size_t)(tj * 64 + rr) * 1024 + ti * 64 + cc + i] = tl[cc + i][rr];
    } else if (bid < 2304) {
        int b = bid - 2272;
        int j = tid * 4;
        for (int i = 0; i < 4; ++i) {
            int k = j + i;
            float hv = (k < 512) ? h0[(size_t)b * 512 + k] : h0[(size_t)(32 + b) * 512 + (k - 512)];
            float cv = (k < 512) ? c0[(size_t)b * 512 + k] : c0[(size_t)(32 + b) * 512 + (k - 512)];
            cF[b * 1024 + k] = cv;
            hb[b * 1024 + k] = f2bf(hv);
        }
    } else {
        size_t i = (size_t)(bid - 2304) * 1024 + tid * 4;
        f32x4 v = *(const f32x4*)(enc + i);
        short4v o;
        o[0]=(short)f2bf(v[0]); o[1]=(short)f2bf(v[1]);
        o[2]=(short)f2bf(v[2]); o[3]=(short)f2bf(v[3]);
        *(short4v*)(enc16 + i) = o;
    }
}

// ---------------------------------------------------------------------------
// k_mm: xg-GEMM [0,512) and M-GEMM [512,768), LDS B-panels (round-14 proven).
// ---------------------------------------------------------------------------
__global__ void __launch_bounds__(512, 1)
k_mm(const u16* __restrict__ xrow, const float* __restrict__ Wih,
     const float* __restrict__ bih, const float* __restrict__ bhh, u16* __restrict__ xg,
     const u16* __restrict__ enc16, const u16* __restrict__ WT, float* __restrict__ Mf)
{
    extern __shared__ char Bl[];
    const int tid = threadIdx.x;
    const int wv = tid >> 6, l = tid & 63, lr = l & 15, lq = l >> 4;
    const int bx = blockIdx.x;
    const bool isXG = bx < 512;
    int mt, nt;
    const u16* Asrc;
    if (isXG) { mt = bx & 7;          nt = bx >> 3; Asrc = xrow;  }
    else      { int mb = bx - 512; mt = mb & 15; nt = mb >> 4; Asrc = enc16; }

    if (isXG) {
        for (int u = tid; u < 8192; u += 512) {
            int row = u >> 7, c8 = (u & 127) * 8;
            *(short8*)(Bl + swz2k(row, c8 * 2)) = cvt8(Wih + (size_t)(nt * 64 + row) * 1024 + c8);
        }
    } else {
        for (int u = tid; u < 8192; u += 512) {
            int row = u >> 7, c8 = (u & 127) * 8;
            *(short8*)(Bl + swz2k(row, c8 * 2)) = *(const short8*)(WT + (size_t)(nt * 64 + row) * 1024 + c8);
        }
    }
    __syncthreads();

    const int r0 = mt * 256 + wv * 32;
    int rA0 = r0 + lr, rA1 = r0 + 16 + lr;
    if (isXG) { if (rA0 > 2015) rA0 = 2015; if (rA1 > 2015) rA1 = 2015; }
    const u16* a0 = Asrc + (size_t)rA0 * 1024 + lq * 8;
    const u16* a1 = Asrc + (size_t)rA1 * 1024 + lq * 8;
    short8 aq0[4], aq1[4];
#pragma unroll
    for (int d = 0; d < 4; ++d) {
        aq0[d] = *(const short8*)(a0 + d * 32);
        aq1[d] = *(const short8*)(a1 + d * 32);
    }
    f32x4 acc[2][4];
#pragma unroll
    for (int rg = 0; rg < 2; ++rg)
#pragma unroll
        for (int nf = 0; nf < 4; ++nf) acc[rg][nf] = (f32x4){0.f, 0.f, 0.f, 0.f};

#pragma unroll
    for (int k = 0; k < 32; ++k) {
        short8 av0 = aq0[k & 3], av1 = aq1[k & 3];
        if (k + 4 < 32) {
            aq0[k & 3] = *(const short8*)(a0 + (k + 4) * 32);
            aq1[k & 3] = *(const short8*)(a1 + (k + 4) * 32);
        }
#pragma unroll
        for (int nf = 0; nf < 4; ++nf) {
            short8 bv = *(const short8*)(Bl + swz2k(nf * 16 + lr, (lq * 8 + k * 32) * 2));
            acc[0][nf] = __builtin_amdgcn_mfma_f32_16x16x32_bf16(av0, bv, acc[0][nf], 0, 0, 0);
            acc[1][nf] = __builtin_amdgcn_mfma_f32_16x16x32_bf16(av1, bv, acc[1][nf], 0, 0, 0);
        }
    }

    if (isXG) {
#pragma unroll
        for (int rg = 0; rg < 2; ++rg)
#pragma unroll
        for (int nf = 0; nf < 4; ++nf) {
            int n = nt * 64 + nf * 16 + lr;
            float bias = bih[n] + bhh[n];
#pragma unroll
            for (int q = 0; q < 4; ++q) {
                int rr = r0 + rg * 16 + lq * 4 + q;
                if (rr < 2016) xg[(size_t)rr * 4096 + n] = f2bf(acc[rg][nf][q] + bias);
            }
        }
    } else {
#pragma unroll
        for (int rg = 0; rg < 2; ++rg)
#pragma unroll
        for (int nf = 0; nf < 4; ++nf) {
            int n = nt * 64 + nf * 16 + lr;
#pragma unroll
            for (int q = 0; q < 4; ++q)
                Mf[(size_t)(r0 + rg * 16 + lq * 4 + q) * 1024 + n] = acc[rg][nf][q];
        }
    }
}

// ---------------------------------------------------------------------------
// combine 16 half-chunk partials -> ctxA[tstore] (tid<32)
// ---------------------------------------------------------------------------
DEV void combine16(int b, int ch, int tstore, int tid, int slot,
                   const float* __restrict__ pCtx, const float* __restrict__ pMx,
                   const float* __restrict__ pSm, u16* __restrict__ ctxA)
{
    if (tid >= 32) return;
    const float* mx = pMx + (size_t)slot * 512 + b * 16;
    const float* sm = pSm + (size_t)slot * 512 + b * 16;
    const float* pc = pCtx + (size_t)slot * (32 * 16 * 1024) + (size_t)b * 16 * 1024;
    float m16[16], s16[16];
#pragma unroll
    for (int c = 0; c < 16; ++c) { m16[c] = ldg_f32(mx + c); s16[c] = ldg_f32(sm + c); }
    float gm = -1e30f;
#pragma unroll
    for (int c = 0; c < 16; ++c) gm = fmaxf(gm, m16[c]);
    float wsum = 0.f, e[16];
#pragma unroll
    for (int c = 0; c < 16; ++c) { e[c] = expf(m16[c] - gm); wsum += s16[c] * e[c]; }
    float inv = 1.f / wsum;
    int j = ch * 128 + tid * 4;
    f32x4 a = {0.f, 0.f, 0.f, 0.f};
#pragma unroll
    for (int c = 0; c < 16; ++c) {
        union { u64 q[2]; f32x4 v; } u;
        const u64* p = (const u64*)(pc + (size_t)c * 1024 + j);
        u.q[0] = ldg_u64(p); u.q[1] = ldg_u64(p + 1);
        float s = e[c] * inv;
        a[0] += u.v[0] * s; a[1] += u.v[1] * s; a[2] += u.v[2] * s; a[3] += u.v[3] * s;
    }
    short4v o4;
    o4[0] = (short)f2bf(a[0]); o4[1] = (short)f2bf(a[1]);
    o4[2] = (short)f2bf(a[2]); o4[3] = (short)f2bf(a[3]);
    *(short4v*)(ctxA + ((size_t)tstore * 32 + b) * 1024 + j) = o4;
}

// ---------------------------------------------------------------------------
// k_loop: wave-specialized persistent kernel (round-7/14 known-good).
// ---------------------------------------------------------------------------
#define ML_PITCH 1028
#define EL_PITCH 1032
#define ML_BYTES (16 * ML_PITCH * 4)
#define EL_BYTES (16 * EL_PITCH * 2)
#define DYN_BYTES (ML_BYTES + EL_BYTES)

__global__ void __launch_bounds__(256, 1)
k_loop(const u16* __restrict__ xg, const float* __restrict__ Mf,
       u16* __restrict__ ctxA, u16* __restrict__ hAll,
       u16* __restrict__ hb, float* __restrict__ hF, float* __restrict__ cF,
       float* __restrict__ pCtx, float* __restrict__ pMx, float* __restrict__ pSm,
       const float* __restrict__ enc, const float* __restrict__ Whh,
       const int* __restrict__ slen, float* __restrict__ out, u32* __restrict__ bar)
{
    const int bid = blockIdx.x, tid = threadIdx.x;
    const int wv = tid >> 6, l = tid & 63, lr = l & 15, lq = l >> 4;
    u32* slots = bar;

    extern __shared__ char smem[];
    float* Ml = (float*)smem;                 // [16][ML_PITCH]
    u16*   El = (u16*)(smem + ML_BYTES);      // [16][EL_PITCH]

    __shared__ float red[2][32][16];

    const int b_at = bid >> 3, ch = bid & 7, s0 = ch * 16;

    // ---- prologue ----
    short8 breg[16];
    if (wv < 2) {
        const float* wsrc = Whh + ((size_t)((lr >> 2) * 1024 + bid * 4 + (lr & 3))) * 1024
                                + wv * 512 + lq * 8;
#pragma unroll
        for (int ks = 0; ks < 16; ++ks)
            breg[ks] = cvt8(wsrc + ks * 32);
    }
    {   // M slice (fp32)
        int row = tid >> 4;
        const float* src = Mf + (size_t)(b_at * 128 + s0 + row) * 1024;
        float* dst = &Ml[row * ML_PITCH];
#pragma unroll
        for (int i = 0; i < 16; ++i) {
            int c = (tid & 15) * 4 + i * 64;
            *(f32x4*)(dst + c) = *(const f32x4*)(src + c);
        }
    }
    {   // enc slice (bf16)
        int row = tid >> 4;
        const float* src = enc + (size_t)(b_at * 128 + s0 + row) * 1024;
        u16* dst = &El[row * EL_PITCH];
#pragma unroll
        for (int i = 0; i < 16; ++i) {
            int c = (tid & 15) * 4 + i * 64;
            f32x4 v = *(const f32x4*)(src + c);
            short4v o;
            o[0]=(short)f2bf(v[0]); o[1]=(short)f2bf(v[1]);
            o[2]=(short)f2bf(v[2]); o[3]=(short)f2bf(v[3]);
            *(short4v*)(dst + c) = o;
        }
    }

    const int lb = tid & 31, lkk = (tid >> 5) - 4;
    const int lkidx = bid * 4 + lkk;
    float creg = 0.f;
    float xgv[4] = {0,0,0,0};
    if (tid >= 128) {
        creg = cF[lb * 1024 + lkidx];
#pragma unroll
        for (int g = 0; g < 4; ++g)
            xgv[g] = bf2f(xg[((size_t)lb) * 4096 + g * 1024 + lkidx]);   // t=0
    }
    int vlen = slen[b_at]; if (vlen < 1) vlen = 1;
    __syncthreads();

    for (int t = 0; t < 64; ++t) {
        if (t >= 1) bar_wait(slots, (u32)t, tid);

        if (t < 63 && wv < 2) {
            // ---- gates GEMM (waves 0-1, K split 2-way, 16-deep pipeline) ----
            const u16* hrd = hb + (size_t)(t & 1) * (32 * 1024);
            const u16* p0 = hrd + lr * 1024 + wv * 512 + lq * 8;
            const u16* p1 = p0 + 16 * 1024;
            i32x4 a0b[16], a1b[16];
#pragma unroll
            for (int ks = 0; ks < 16; ++ks) {
                ldcc4i(&a0b[ks], p0 + ks * 32);
                ldcc4i(&a1b[ks], p1 + ks * 32);
            }
            f32x4 acc0 = {0,0,0,0}, acc1 = {0,0,0,0};
#pragma unroll
            for (int ks = 0; ks < 16; ++ks) {
                asm volatile("s_waitcnt vmcnt(%0)" :: "i"(30 - 2 * ks) : "memory");
                __builtin_amdgcn_sched_barrier(0);
                acc0 = __builtin_amdgcn_mfma_f32_16x16x32_bf16(as_s8(a0b[ks]), breg[ks], acc0, 0, 0, 0);
                acc1 = __builtin_amdgcn_mfma_f32_16x16x32_bf16(as_s8(a1b[ks]), breg[ks], acc1, 0, 0, 0);
            }
#pragma unroll
            for (int q = 0; q < 4; ++q) {
                red[wv][lq * 4 + q][lr] = acc0[q];
                red[wv][16 + lq * 4 + q][lr] = acc1[q];
            }
        }

        if (t >= 1 && wv >= 2) {
            // ---- attention for h_t (waves 2-3, fully in-wave) ----
            const int w = wv - 2;
            const int lane = l;
            const float* hrow = hF + (size_t)(t & 1) * (32 * 1024) + b_at * 1024;
            f32x4 hreg[4];
            ldcc4f(&hreg[0], hrow + 0 * 256 + lane * 4);
            ldcc4f(&hreg[1], hrow + 1 * 256 + lane * 4);
            ldcc4f(&hreg[2], hrow + 2 * 256 + lane * 4);
            ldcc4f(&hreg[3], hrow + 3 * 256 + lane * 4);
            asm volatile("s_waitcnt vmcnt(0)" ::: "memory");
            __builtin_amdgcn_sched_barrier(0);
            float part[8];
#pragma unroll
            for (int r = 0; r < 8; ++r) {
                const float* mrow = &Ml[(w * 8 + r) * ML_PITCH];
                float s = 0.f;
#pragma unroll
                for (int c = 0; c < 4; ++c) {
                    f32x4 m4 = *(const f32x4*)(mrow + c * 256 + lane * 4);
                    s += m4[0]*hreg[c][0] + m4[1]*hreg[c][1] + m4[2]*hreg[c][2] + m4[3]*hreg[c][3];
                }
                part[r] = s;
            }
#pragma unroll
            for (int d = 1; d < 64; d <<= 1) {
#pragma unroll
                for (int r = 0; r < 8; ++r) part[r] += __shfl_xor(part[r], d);
            }
            int sgb = s0 + w * 8;
            float mc = -1e30f;
#pragma unroll
            for (int r = 0; r < 8; ++r) {
                part[r] = (sgb + r < vlen) ? part[r] : -1e30f;
                mc = fmaxf(mc, part[r]);
            }
            float e8[8]; float psum = 0.f;
#pragma unroll
            for (int r = 0; r < 8; ++r) {
                e8[r] = (part[r] > -1e29f) ? expf(part[r] - mc) : 0.f;
                psum += e8[r];
            }
            f32x4 ca[4] = {{0,0,0,0},{0,0,0,0},{0,0,0,0},{0,0,0,0}};
#pragma unroll
            for (int r = 0; r < 8; ++r) {
                float p = e8[r];
                const u16* erow = &El[(w * 8 + r) * EL_PITCH];
#pragma unroll
                for (int c = 0; c < 4; ++c) {
                    short4v e4 = *(const short4v*)(erow + c * 256 + lane * 4);
                    ca[c][0] += p * bf2f((u16)e4[0]);
                    ca[c][1] += p * bf2f((u16)e4[1]);
                    ca[c][2] += p * bf2f((u16)e4[2]);
                    ca[c][3] += p * bf2f((u16)e4[3]);
                }
            }
            float* pd = pCtx + (size_t)(t & 3) * (32 * 16 * 1024)
                             + (size_t)(b_at * 16 + ch * 2 + w) * 1024;
#pragma unroll
            for (int c = 0; c < 4; ++c) {
                union { f32x4 v; u64 q[2]; } cu; cu.v = ca[c];
                u64* p = (u64*)(pd + c * 256 + lane * 4);
                stg_u64(p, cu.q[0]);
                stg_u64(p + 1, cu.q[1]);
            }
            if (lane == 0) {
                stg_f32(&pMx[(size_t)(t & 3) * 512 + b_at * 16 + ch * 2 + w], mc);
                stg_f32(&pSm[(size_t)(t & 3) * 512 + b_at * 16 + ch * 2 + w], psum);
            }
        }
        __syncthreads();

        if (t < 63 && tid >= 128) {
            // ---- LSTM elementwise ----
            float G[4];
#pragma unroll
            for (int g = 0; g < 4; ++g) {
                int n = g * 4 + lkk;
                G[g] = red[0][lb][n] + red[1][lb][n] + xgv[g];
            }
            float iS = sigm(G[0]), fS = sigm(G[1]), gT = tanhf(G[2]), oS = sigm(G[3]);
            float cn = fS * creg + iS * gT;
            float hn = oS * tanhf(cn);
            creg = cn;
            u16 h16 = f2bf(hn);
            int sl = (t + 1) & 1;
            stg_f32(&hF[(size_t)sl * (32 * 1024) + lb * 1024 + lkidx], hn);
            stg_u16(&hb[(size_t)sl * (32 * 1024) + lb * 1024 + lkidx], h16);
            hAll[((size_t)t * 32 + lb) * 1024 + lkidx] = h16;
        }

        bar_arrive(slots, (u32)(t + 1), bid, tid);

        // ---- shadow: combine + xg prefetch overlap barrier propagation ----
        if (t >= 2)
            combine16(b_at, ch, t - 2, tid, (t - 1) & 3, pCtx, pMx, pSm, ctxA);
        if (t < 62 && tid >= 128) {
#pragma unroll
            for (int g = 0; g < 4; ++g)
                xgv[g] = bf2f(xg[((size_t)(t + 1) * 32 + lb) * 4096 + g * 1024 + lkidx]);
        }
    }

    bar_wait(slots, 64u, tid);
    combine16(b_at, ch, 62, tid, 3, pCtx, pMx, pSm, ctxA);
    if (bid >= 32 && bid < 64) {
        int b = bid - 32, j = tid * 4;
#pragma unroll
        for (int i = 0; i < 4; ++i)
            out[2064384 + b * 1024 + j + i] = ldg_f32(&hF[(size_t)1 * (32 * 1024) + b * 1024 + j + i]);
    }
    if (tid >= 128)
        out[2064384 + 32768 + lb * 1024 + lkidx] = creg;
}

// ---------------------------------------------------------------------------
// k_out: output GEMM, tile 256x32, LDS B-panel (round-14 proven).
// ---------------------------------------------------------------------------
__global__ void __launch_bounds__(512, 1)
k_out(const u16* __restrict__ ctxA, const u16* __restrict__ hAll,
      const float* __restrict__ Wao, float* __restrict__ out)
{
    extern __shared__ char Bl[];
    const int tid = threadIdx.x;
    const int wv = tid >> 6, l = tid & 63, lr = l & 15, lq = l >> 4;
    const int bx = blockIdx.x;
    const int mt = bx & 7, nt = bx >> 3;   // 8 m-tiles x 32 n-tiles

    for (int u = tid; u < 8192; u += 512) {
        int row = u >> 8, c8 = (u & 255) * 8;
        *(short8*)(Bl + swz4k(row, c8 * 2)) = cvt8(Wao + (size_t)(nt * 32 + row) * 2048 + c8);
    }
    __syncthreads();

    const int r0 = mt * 256 + wv * 32;
    int rA0 = r0 + lr;       if (rA0 > 2015) rA0 = 2015;
    int rA1 = r0 + 16 + lr;  if (rA1 > 2015) rA1 = 2015;
    const u16* ac0 = ctxA + (size_t)rA0 * 1024 + lq * 8;
    const u16* ah0 = hAll + (size_t)rA0 * 1024 + lq * 8;
    const u16* ac1 = ctxA + (size_t)rA1 * 1024 + lq * 8;
    const u16* ah1 = hAll + (size_t)rA1 * 1024 + lq * 8;

    short8 aq0[4], aq1[4];
#pragma unroll
    for (int d = 0; d < 4; ++d) {
        aq0[d] = *(const short8*)(ac0 + d * 32);
        aq1[d] = *(const short8*)(ac1 + d * 32);
    }
    f32x4 acc[2][2];
#pragma unroll
    for (int rg = 0; rg < 2; ++rg)
#pragma unroll
        for (int nf = 0; nf < 2; ++nf) acc[rg][nf] = (f32x4){0.f, 0.f, 0.f, 0.f};

#pragma unroll
    for (int k = 0; k < 64; ++k) {
        short8 av0 = aq0[k & 3], av1 = aq1[k & 3];
        if (k + 4 < 64) {
            int kn = k + 4;
            if (kn < 32) {
                aq0[k & 3] = *(const short8*)(ac0 + kn * 32);
                aq1[k & 3] = *(const short8*)(ac1 + kn * 32);
            } else {
                aq0[k & 3] = *(const short8*)(ah0 + (kn - 32) * 32);
                aq1[k & 3] = *(const short8*)(ah1 + (kn - 32) * 32);
            }
        }
#pragma unroll
        for (int nf = 0; nf < 2; ++nf) {
            short8 bv = *(const short8*)(Bl + swz4k(nf * 16 + lr, (lq * 8 + k * 32) * 2));
            acc[0][nf] = __builtin_amdgcn_mfma_f32_16x16x32_bf16(av0, bv, acc[0][nf], 0, 0, 0);
            acc[1][nf] = __builtin_amdgcn_mfma_f32_16x16x32_bf16(av1, bv, acc[1][nf], 0, 0, 0);
        }
    }
#pragma unroll
    for (int rg = 0; rg < 2; ++rg)
#pragma unroll
    for (int nf = 0; nf < 2; ++nf) {
        int n = nt * 32 + nf * 16 + lr;
#pragma unroll
        for (int q = 0; q < 4; ++q) {
            int rr = r0 + rg * 16 + lq * 4 + q;
            if (rr < 2016) {
                int t = rr >> 5, b = rr & 31;
                out[(size_t)b * 64512 + t * 1024 + n] = tanhf(acc[rg][nf][q]);
            }
        }
    }
}

// ---------------------------------------------------------------------------
extern "C" void kernel_launch(void* const* d_in, const int* in_sizes, int n_in,
                              void* d_out, int out_size, void* d_ws, size_t ws_size,
                              hipStream_t stream)
{
    (void)in_sizes; (void)n_in; (void)out_size; (void)ws_size;
    const int*   tgt  = (const int*)d_in[0];
    const float* h0   = (const float*)d_in[1];
    const float* c0   = (const float*)d_in[2];
    const float* enc  = (const float*)d_in[3];
    const int*   slen = (const int*)d_in[4];
    const float* emb  = (const float*)d_in[5];
    const float* Wih  = (const float*)d_in[6];
    const float* Whh  = (const float*)d_in[7];
    const float* bih  = (const float*)d_in[8];
    const float* bhh  = (const float*)d_in[9];
    const float* Wai  = (const float*)d_in[10];
    const float* Wao  = (const float*)d_in[11];
    float* out = (float*)d_out;

    char* ws = (char*)d_ws;
    size_t off = 0;
    auto alloc = [&](size_t bytes) -> char* {
        char* p = ws + off; off += (bytes + 255) & ~(size_t)255; return p;
    };
    u16*   enc16 = (u16*)  alloc(4096UL * 1024 * 2);
    u16*   xrow  = (u16*)  alloc(2016UL * 1024 * 2);
    u16*   WT    = (u16*)  alloc(1024UL * 1024 * 2);
    u16*   xg    = (u16*)  alloc(2016UL * 4096 * 2);
    float* Mf    = (float*)alloc(4096UL * 1024 * 4);
    u16*   hb    = (u16*)  alloc(2UL * 32 * 1024 * 2);
    float* hF    = (float*)alloc(2UL * 32 * 1024 * 4);
    float* cF    = (float*)alloc(32UL * 1024 * 4);
    u16*   hAll  = (u16*)  alloc(2016UL * 1024 * 2);
    u16*   ctxA  = (u16*)  alloc(2016UL * 1024 * 2);
    float* pCtx  = (float*)alloc(4UL * 32 * 16 * 1024 * 4);
    float* pMx   = (float*)alloc(4UL * 512 * 4);
    float* pSm   = (float*)alloc(4UL * 512 * 4);
    u32*   bar   = (u32*)  alloc(2048);

    static int lds_set = 0;
    if (!lds_set) {
        (void)hipFuncSetAttribute((const void*)k_loop,
                                  hipFuncAttributeMaxDynamicSharedMemorySize, DYN_BYTES);
        (void)hipFuncSetAttribute((const void*)k_mm,
                                  hipFuncAttributeMaxDynamicSharedMemorySize, 131072);
        (void)hipFuncSetAttribute((const void*)k_out,
                                  hipFuncAttributeMaxDynamicSharedMemorySize, 131072);
        lds_set = 1;
    }

    hipMemsetAsync(bar, 0, 2048, stream);
    hipLaunchKernelGGL(k_prep, dim3(6400), dim3(256), 0, stream,
                       enc, enc16, tgt, emb, xrow, Wai, WT, h0, c0, cF, hb);
    hipLaunchKernelGGL(k_mm, dim3(768), dim3(512), 131072, stream,
                       xrow, Wih, bih, bhh, xg, enc16, WT, Mf);

    void* kargs[] = { (void*)&xg, (void*)&Mf, (void*)&ctxA, (void*)&hAll, (void*)&hb,
                      (void*)&hF, (void*)&cF, (void*)&pCtx, (void*)&pMx, (void*)&pSm,
                      (void*)&enc, (void*)&Whh, (void*)&slen, (void*)&out, (void*)&bar };
    hipLaunchCooperativeKernel((const void*)k_loop, dim3(256), dim3(256), kargs, DYN_BYTES, stream);

    hipLaunchKernelGGL(k_out, dim3(256), dim3(512), 131072, stream, ctxA, hAll, Wao, out);
}